// Round 7
// baseline (2277.000 us; speedup 1.0000x reference)
//
#include <hip/hip_runtime.h>

// Grid constants (padded 66^3)
#define GD   66
#define GHW  (66*66)
#define GDHW (66*66*66)
#define CI   32
#define CO   32
#define NBINS (2*64*64*64)      // batch * 64^3 = 524288 bins
#define NSCAN_BLOCKS 2048       // NBINS / 256

__device__ __forceinline__ void atomAdd(float* p, float v) {
    unsafeAtomicAdd(p, v);      // native global_atomic_add_f32 on gfx950
}

// ---------------- sort-gather path ----------------
// r0/r1: scatter hits the L2 atomic-op wall (345.6M ops ~1/channel/cycle ->
// 1117us floor). r3: gather latency-bound. r4: per-bin slot machinery.
// r6: VGPR_Count=64 exposed that kreg[3][32] (96 floats) was demoted to
// scratch/remat -> ~96 extra cached loads per particle-visit; VALUBusy
// halved, dur unchanged. r7 (this): ok as MIDDLE loop so only kreg[32]
// (32 VGPRs) is live, + __launch_bounds__(256,4) caps 128 VGPR -> K truly
// register-resident at 4 waves/SIMD.

// K1: histogram + per-particle (bin, rank)
__global__ __launch_bounds__(256) void hist_kernel(
    const float* __restrict__ pos, unsigned* __restrict__ counts,
    unsigned* __restrict__ binA, unsigned* __restrict__ rankA,
    int N, int total)
{
    int gp = blockIdx.x*256 + threadIdx.x;
    if (gp >= total) return;
    float px = pos[gp*3+0]*64.f, py = pos[gp*3+1]*64.f, pz = pos[gp*3+2]*64.f;
    int bx = (int)px, by = (int)py, bz = (int)pz;     // base in [0,63]
    int b  = (gp >= N) ? 1 : 0;
    unsigned bin = (((unsigned)(b*64 + bx))*64u + (unsigned)by)*64u + (unsigned)bz;
    unsigned r = atomicAdd(&counts[bin], 1u);
    binA[gp] = bin; rankA[gp] = r;
}

// S1: per-block (256 bins) local exclusive scan + block sums
__global__ __launch_bounds__(256) void scan1_kernel(
    const unsigned* __restrict__ counts, unsigned* __restrict__ offs,
    unsigned* __restrict__ bsum)
{
    __shared__ unsigned ws[4];
    int i = blockIdx.x*256 + threadIdx.x;
    int lane = threadIdx.x & 63, wid = threadIdx.x >> 6;
    unsigned v = counts[i], s = v;
    #pragma unroll
    for (int d = 1; d < 64; d <<= 1) { unsigned n = __shfl_up(s, d, 64); if (lane >= d) s += n; }
    if (lane == 63) ws[wid] = s;
    __syncthreads();
    if (threadIdx.x == 0) {
        unsigned r = 0;
        for (int w = 0; w < 4; ++w) { unsigned t = ws[w]; ws[w] = r; r += t; }
        bsum[blockIdx.x] = r;
    }
    __syncthreads();
    offs[i] = ws[wid] + s - v;
}

// S2: single block scans the 2048 block sums (exclusive, in place)
__global__ __launch_bounds__(256) void scan2_kernel(unsigned* __restrict__ bsum)
{
    __shared__ unsigned ws[4];
    __shared__ unsigned runsh;
    if (threadIdx.x == 0) runsh = 0;
    __syncthreads();
    int lane = threadIdx.x & 63, wid = threadIdx.x >> 6;
    for (int c = 0; c < NSCAN_BLOCKS; c += 256) {
        unsigned v = bsum[c + threadIdx.x], s = v;
        #pragma unroll
        for (int d = 1; d < 64; d <<= 1) { unsigned n = __shfl_up(s, d, 64); if (lane >= d) s += n; }
        if (lane == 63) ws[wid] = s;
        __syncthreads();
        unsigned run = runsh;
        __syncthreads();
        if (threadIdx.x == 0) {
            unsigned r = 0;
            for (int w = 0; w < 4; ++w) { unsigned t = ws[w]; ws[w] = r; r += t; }
            runsh = run + r;
        }
        __syncthreads();
        bsum[c + threadIdx.x] = run + ws[wid] + s - v;
        __syncthreads();
    }
}

// S3: add block prefix; set offs[NBINS] = total
__global__ __launch_bounds__(256) void scan3_kernel(
    unsigned* __restrict__ offs, const unsigned* __restrict__ bsum, int total)
{
    int i = blockIdx.x*256 + threadIdx.x;
    offs[i] += bsum[blockIdx.x];
    if (i == 0) offs[NBINS] = (unsigned)total;
}

// KT: transpose kernel weights K[t3][ci][co] -> KT[t3][co][ci] so a lane's
// 32 ci values are CONTIGUOUS (8 float4 loads instead of 32 strided).
__global__ __launch_bounds__(256) void ktr_kernel(
    const float* __restrict__ kern, float* __restrict__ KT)
{
    int i = blockIdx.x*256 + threadIdx.x;       // 27*32*32 = 27648
    if (i >= 27*32*32) return;
    int co = i & 31, ci = (i >> 5) & 31, t3 = i >> 10;
    KT[((size_t)t3*32 + co)*32 + ci] = kern[((size_t)t3*32 + ci)*32 + co];
}

// K3: reorder into bin-sorted SoA: X[p][32], W[p][9], GZ[p] (bin z, u8)
__global__ __launch_bounds__(256) void reorder_kernel(
    const float* __restrict__ x, const float* __restrict__ pos,
    const unsigned* __restrict__ offs, const unsigned* __restrict__ binA,
    const unsigned* __restrict__ rankA,
    float* __restrict__ X, float* __restrict__ W, unsigned char* __restrict__ GZ,
    int total)
{
    int gp = blockIdx.x*256 + threadIdx.x;
    if (gp >= total) return;
    unsigned bin = binA[gp];
    unsigned dst = offs[bin] + rankA[gp];
    const float4* xs = (const float4*)(x + (size_t)gp*32);
    float4* xd = (float4*)(X + (size_t)dst*32);
    #pragma unroll
    for (int i = 0; i < 8; ++i) xd[i] = xs[i];
    float px = pos[gp*3+0]*64.f, py = pos[gp*3+1]*64.f, pz = pos[gp*3+2]*64.f;
    int bx = (int)px, by = (int)py, bz = (int)pz;
    float fx = px-bx-0.5f, fy = py-by-0.5f, fz = pz-bz-0.5f;
    float* w = W + (size_t)dst*9;
    w[0]=0.5f*(0.5f-fx)*(0.5f-fx); w[1]=0.75f-fx*fx; w[2]=0.5f*(0.5f+fx)*(0.5f+fx);
    w[3]=0.5f*(0.5f-fy)*(0.5f-fy); w[4]=0.75f-fy*fy; w[5]=0.5f*(0.5f+fy)*(0.5f+fy);
    w[6]=0.5f*(0.5f-fz)*(0.5f-fz); w[7]=0.75f-fz*fz; w[8]=0.5f*(0.5f+fz)*(0.5f+fz);
    GZ[dst] = (unsigned char)(bin & 63u);
}

// K4 v4: gather. Block = (b, cx, cy) full z-column. Loops: t-pair (9) ->
// ok (3, kreg[32] register-resident) -> particle streak (contiguous in
// sorted order, 4 waves x 2 slots, unroll 2). Per visit: 8 float4 X loads
// (L1-hit after first ok), 32 FMAs, 1 ds_add_f32 into tile[gz+ok][co].
// __launch_bounds__(256,4): cap 128 VGPR so kreg NEVER spills (r6 lesson:
// VGPR=64 meant kreg[3][32] was demoted to per-use reloads).
__global__ __launch_bounds__(256, 4) void gather_kernel(
    const float* __restrict__ X, const float* __restrict__ W,
    const unsigned char* __restrict__ GZ, const unsigned* __restrict__ offs,
    const float* __restrict__ KT, const float* __restrict__ bias,
    float* __restrict__ out)
{
    __shared__ float tile[GD][33];              // 8712 B
    int bid = blockIdx.x;
    const int cy = bid % 66; bid /= 66;
    const int cx = bid % 66;
    const int b  = bid / 66;

    const int lane = threadIdx.x & 63;
    const int co   = lane & 31;
    const int slot = lane >> 5;                 // particle slot within wave
    const int w    = threadIdx.x >> 6;          // wave id 0..3
    const float bco = bias[co];

    for (int i = threadIdx.x; i < GD*33; i += 256) (&tile[0][0])[i] = 0.f;
    __syncthreads();

    for (int t = 0; t < 9; ++t) {               // t = oi*3 + oj
        const int oi = t/3, oj = t%3;
        const int gx = cx - oi, gy = cy - oj;
        if ((unsigned)gx > 63u || (unsigned)gy > 63u) continue;   // block-uniform

        const unsigned colb = (((unsigned)(b*64 + gx))*64u + (unsigned)gy)*64u;
        const unsigned s = offs[colb], e = offs[colb + 64];

        for (int ok = 0; ok < 3; ++ok) {
            // K column for this (oi,oj,ok): 32 VGPRs, float4-loaded from KT.
            float kreg[32];
            {
                const float4* kp = (const float4*)(KT + ((size_t)(t*3+ok)*32 + co)*32);
                #pragma unroll
                for (int i = 0; i < 8; ++i) {
                    float4 v = kp[i];
                    kreg[4*i+0]=v.x; kreg[4*i+1]=v.y; kreg[4*i+2]=v.z; kreg[4*i+3]=v.w;
                }
            }

            #pragma unroll 2
            for (unsigned p = s + (unsigned)(w*2 + slot); p < e; p += 8) {
                const float4* xp = (const float4*)(X + (size_t)p*32);
                const float*  wp = W + (size_t)p*9;
                const int gz = (int)GZ[p];
                const float wfull = wp[oi]*wp[3+oj]*wp[6+ok];
                float d = bco;
                #pragma unroll
                for (int i = 0; i < 8; ++i) {
                    float4 v = xp[i];
                    d += v.x*kreg[4*i+0];
                    d += v.y*kreg[4*i+1];
                    d += v.z*kreg[4*i+2];
                    d += v.w*kreg[4*i+3];
                }
                atomicAdd(&tile[gz + ok][co], wfull*d);   // ds_add_f32, 32 banks
            }
        }
    }

    __syncthreads();
    const size_t obase = (size_t)b*32*GDHW + (size_t)(cx*GHW + cy*GD);
    for (int idx = threadIdx.x; idx < 32*GD; idx += 256) {
        const int co2 = idx / GD, z2 = idx % GD;    // consecutive lanes -> consecutive z
        out[obase + (size_t)co2*GDHW + z2] = tile[z2][co2];
    }
}

// ---------------- fallback: direct atomic scatter ----------------
__global__ __launch_bounds__(256) void p2g_fallback(
    const float* __restrict__ x, const float* __restrict__ pos,
    const float* __restrict__ kern, const float* __restrict__ bias,
    float* __restrict__ dst, int N, int nPairs)
{
    const int co   = threadIdx.x & 31;
    const int half = threadIdx.x >> 5;
    const float bco = bias[co];
    const int halvesTotal = gridDim.x * 8;

    for (int t = 0; t < 9; ++t) {
        const int oi = t / 3, oj = t - 3*oi;
        float kreg[3][32];
        #pragma unroll
        for (int ok = 0; ok < 3; ++ok) {
            const float* kp = kern + (size_t)(t*3 + ok)*1024 + co;
            #pragma unroll
            for (int ci = 0; ci < 32; ++ci) kreg[ok][ci] = kp[ci*32];
        }
        for (int pp = blockIdx.x*8 + half; pp < nPairs; pp += halvesTotal) {
            const int g0 = pp*2;
            float xr[2][32];
            #pragma unroll
            for (int p = 0; p < 2; ++p) {
                const float4* xp = (const float4*)(x + (size_t)(g0+p)*CI);
                #pragma unroll
                for (int i = 0; i < 8; ++i) {
                    float4 v = xp[i];
                    xr[p][4*i+0]=v.x; xr[p][4*i+1]=v.y; xr[p][4*i+2]=v.z; xr[p][4*i+3]=v.w;
                }
            }
            float wxy[2], wz[2][3]; int cb[2], bsel[2];
            #pragma unroll
            for (int p = 0; p < 2; ++p) {
                const int gp = g0 + p;
                float px = pos[gp*3+0]*64.f, py = pos[gp*3+1]*64.f, pz = pos[gp*3+2]*64.f;
                int bx = (int)px, by = (int)py, bz = (int)pz;
                float fx = px-bx-0.5f, fy = py-by-0.5f, fz = pz-bz-0.5f;
                float wx = (oi==0) ? 0.5f*(0.5f-fx)*(0.5f-fx) : (oi==1) ? 0.75f-fx*fx : 0.5f*(0.5f+fx)*(0.5f+fx);
                float wy = (oj==0) ? 0.5f*(0.5f-fy)*(0.5f-fy) : (oj==1) ? 0.75f-fy*fy : 0.5f*(0.5f+fy)*(0.5f+fy);
                wxy[p] = wx*wy;
                wz[p][0]=0.5f*(0.5f-fz)*(0.5f-fz); wz[p][1]=0.75f-fz*fz; wz[p][2]=0.5f*(0.5f+fz)*(0.5f+fz);
                cb[p]   = (bx+oi)*GHW + (by+oj)*GD + bz;
                bsel[p] = (gp >= N) ? 1 : 0;
            }
            float y[3][2];
            #pragma unroll
            for (int ok = 0; ok < 3; ++ok) { y[ok][0] = bco; y[ok][1] = bco; }
            #pragma unroll
            for (int ci = 0; ci < 32; ++ci) {
                float x0 = xr[0][ci], x1 = xr[1][ci];
                #pragma unroll
                for (int ok = 0; ok < 3; ++ok) {
                    float kv = kreg[ok][ci];
                    y[ok][0] += x0*kv; y[ok][1] += x1*kv;
                }
            }
            #pragma unroll
            for (int ok = 0; ok < 3; ++ok) {
                atomAdd(dst + ((size_t)(bsel[0]*32 + co))*GDHW + (size_t)(cb[0]+ok), wxy[0]*wz[0][ok]*y[ok][0]);
                atomAdd(dst + ((size_t)(bsel[1]*32 + co))*GDHW + (size_t)(cb[1]+ok), wxy[1]*wz[1][ok]*y[ok][1]);
            }
        }
    }
}

extern "C" void kernel_launch(void* const* d_in, const int* in_sizes, int n_in,
                              void* d_out, int out_size, void* d_ws, size_t ws_size,
                              hipStream_t stream) {
    const float* x    = (const float*)d_in[0];
    const float* pos  = (const float*)d_in[1];
    const float* kern = (const float*)d_in[2];
    const float* bias = (const float*)d_in[3];
    float* out = (float*)d_out;

    const int N     = in_sizes[0] / (2*CI);   // per-batch particle count
    const int total = 2*N;

    // workspace layout (bytes) -- stays under the proven-available 73.59 MB:
    // KT aliases counts (dead after scan1); GZ is u8.
    const size_t offX    = 0;                                   // X: total*32 f32
    const size_t offW    = offX + (size_t)total*32*4;           // W: total*9 f32
    const size_t offCnt  = offW + (size_t)total*9*4;            // counts: NBINS u32 (KT aliases)
    const size_t offOffs = offCnt + (size_t)NBINS*4;            // offs: NBINS+1 u32
    const size_t offBin  = (offOffs + (size_t)(NBINS+1)*4 + 255) & ~(size_t)255;
    const size_t offRank = offBin + (size_t)total*4;
    const size_t offBsum = offRank + (size_t)total*4;
    const size_t offGZ   = offBsum + (size_t)NSCAN_BLOCKS*4;
    const size_t wsNeed  = offGZ + (size_t)total + 256;

    if (ws_size >= wsNeed) {
        char* wsb = (char*)d_ws;
        float*    X      = (float*)   (wsb + offX);
        float*    W      = (float*)   (wsb + offW);
        unsigned* counts = (unsigned*)(wsb + offCnt);
        float*    KT     = (float*)   (wsb + offCnt);   // alias: counts dead after scan1
        unsigned* offs   = (unsigned*)(wsb + offOffs);
        unsigned* binA   = (unsigned*)(wsb + offBin);
        unsigned* rankA  = (unsigned*)(wsb + offRank);
        unsigned* bsum   = (unsigned*)(wsb + offBsum);
        unsigned char* GZ = (unsigned char*)(wsb + offGZ);

        (void)hipMemsetAsync(counts, 0, (size_t)NBINS*4, stream);
        const int pb = (total + 255)/256;
        hist_kernel   <<<dim3(pb),           dim3(256), 0, stream>>>(pos, counts, binA, rankA, N, total);
        scan1_kernel  <<<dim3(NSCAN_BLOCKS), dim3(256), 0, stream>>>(counts, offs, bsum);
        ktr_kernel    <<<dim3(108),          dim3(256), 0, stream>>>(kern, KT);   // after scan1!
        scan2_kernel  <<<dim3(1),            dim3(256), 0, stream>>>(bsum);
        scan3_kernel  <<<dim3(NSCAN_BLOCKS), dim3(256), 0, stream>>>(offs, bsum, total);
        reorder_kernel<<<dim3(pb),           dim3(256), 0, stream>>>(x, pos, offs, binA, rankA, X, W, GZ, total);
        gather_kernel <<<dim3(2*66*66),      dim3(256), 0, stream>>>(X, W, GZ, offs, KT, bias, out);
    } else {
        (void)hipMemsetAsync(out, 0, (size_t)out_size * sizeof(float), stream);
        const int nPairs = (total + 1) / 2;
        p2g_fallback<<<dim3(2048), dim3(256), 0, stream>>>(x, pos, kern, bias, out, N, nPairs);
    }
}

// Round 9
// 2012.735 us; speedup vs baseline: 1.1313x; 1.1313x over previous
//
#include <hip/hip_runtime.h>

// Grid constants (padded 66^3)
#define GD   66
#define GHW  (66*66)
#define GDHW (66*66*66)
#define CI   32
#define CO   32
#define NBINS (2*64*64*64)      // batch * 64^3 = 524288 bins
#define NSCAN_BLOCKS 2048       // NBINS / 256

__device__ __forceinline__ void atomAdd(float* p, float v) {
    unsafeAtomicAdd(p, v);      // native global_atomic_add_f32 on gfx950
}

// Pin 32 scalar floats into VGPRs (tied scalar constraints are supported;
// tied float4 tuples are NOT -- r8 compile fail). Values become opaque asm
// outputs: the compiler cannot rematerialize/sink the producing loads.
#define PIN32(A) asm volatile("" \
 : "+v"(A[0]),"+v"(A[1]),"+v"(A[2]),"+v"(A[3]),"+v"(A[4]),"+v"(A[5]),"+v"(A[6]),"+v"(A[7]), \
   "+v"(A[8]),"+v"(A[9]),"+v"(A[10]),"+v"(A[11]),"+v"(A[12]),"+v"(A[13]),"+v"(A[14]),"+v"(A[15]), \
   "+v"(A[16]),"+v"(A[17]),"+v"(A[18]),"+v"(A[19]),"+v"(A[20]),"+v"(A[21]),"+v"(A[22]),"+v"(A[23]), \
   "+v"(A[24]),"+v"(A[25]),"+v"(A[26]),"+v"(A[27]),"+v"(A[28]),"+v"(A[29]),"+v"(A[30]),"+v"(A[31]))

// ---------------- sort-gather path ----------------
// r0/r1: scatter = L2 atomic-op wall (345.6M ops -> 1117us floor).
// r3/r4: gather latency/overhead-bound. r6/r7: allocator's occupancy-first
// heuristic sank K into the loop (VGPR 64/40) -> no MLP, ~140M VMEM instrs
// with ok as middle loop. r9 (this): ok INNER (X loaded once per particle
// per t: ~55M VMEM instrs), kreg[3][32]+X pinned via tied scalar asm,
// launch_bounds(256,2) so ~160 VGPRs fit without spill.

// K1: histogram + per-particle (bin, rank)
__global__ __launch_bounds__(256) void hist_kernel(
    const float* __restrict__ pos, unsigned* __restrict__ counts,
    unsigned* __restrict__ binA, unsigned* __restrict__ rankA,
    int N, int total)
{
    int gp = blockIdx.x*256 + threadIdx.x;
    if (gp >= total) return;
    float px = pos[gp*3+0]*64.f, py = pos[gp*3+1]*64.f, pz = pos[gp*3+2]*64.f;
    int bx = (int)px, by = (int)py, bz = (int)pz;     // base in [0,63]
    int b  = (gp >= N) ? 1 : 0;
    unsigned bin = (((unsigned)(b*64 + bx))*64u + (unsigned)by)*64u + (unsigned)bz;
    unsigned r = atomicAdd(&counts[bin], 1u);
    binA[gp] = bin; rankA[gp] = r;
}

// S1: per-block (256 bins) local exclusive scan + block sums
__global__ __launch_bounds__(256) void scan1_kernel(
    const unsigned* __restrict__ counts, unsigned* __restrict__ offs,
    unsigned* __restrict__ bsum)
{
    __shared__ unsigned ws[4];
    int i = blockIdx.x*256 + threadIdx.x;
    int lane = threadIdx.x & 63, wid = threadIdx.x >> 6;
    unsigned v = counts[i], s = v;
    #pragma unroll
    for (int d = 1; d < 64; d <<= 1) { unsigned n = __shfl_up(s, d, 64); if (lane >= d) s += n; }
    if (lane == 63) ws[wid] = s;
    __syncthreads();
    if (threadIdx.x == 0) {
        unsigned r = 0;
        for (int w = 0; w < 4; ++w) { unsigned t = ws[w]; ws[w] = r; r += t; }
        bsum[blockIdx.x] = r;
    }
    __syncthreads();
    offs[i] = ws[wid] + s - v;
}

// S2: single block scans the 2048 block sums (exclusive, in place)
__global__ __launch_bounds__(256) void scan2_kernel(unsigned* __restrict__ bsum)
{
    __shared__ unsigned ws[4];
    __shared__ unsigned runsh;
    if (threadIdx.x == 0) runsh = 0;
    __syncthreads();
    int lane = threadIdx.x & 63, wid = threadIdx.x >> 6;
    for (int c = 0; c < NSCAN_BLOCKS; c += 256) {
        unsigned v = bsum[c + threadIdx.x], s = v;
        #pragma unroll
        for (int d = 1; d < 64; d <<= 1) { unsigned n = __shfl_up(s, d, 64); if (lane >= d) s += n; }
        if (lane == 63) ws[wid] = s;
        __syncthreads();
        unsigned run = runsh;
        __syncthreads();
        if (threadIdx.x == 0) {
            unsigned r = 0;
            for (int w = 0; w < 4; ++w) { unsigned t = ws[w]; ws[w] = r; r += t; }
            runsh = run + r;
        }
        __syncthreads();
        bsum[c + threadIdx.x] = run + ws[wid] + s - v;
        __syncthreads();
    }
}

// S3: add block prefix; set offs[NBINS] = total
__global__ __launch_bounds__(256) void scan3_kernel(
    unsigned* __restrict__ offs, const unsigned* __restrict__ bsum, int total)
{
    int i = blockIdx.x*256 + threadIdx.x;
    offs[i] += bsum[blockIdx.x];
    if (i == 0) offs[NBINS] = (unsigned)total;
}

// KT: transpose kernel weights K[t3][ci][co] -> KT[t3][co][ci] so a lane's
// 32 ci values are CONTIGUOUS (8 float4 loads instead of 32 strided).
__global__ __launch_bounds__(256) void ktr_kernel(
    const float* __restrict__ kern, float* __restrict__ KT)
{
    int i = blockIdx.x*256 + threadIdx.x;       // 27*32*32 = 27648
    if (i >= 27*32*32) return;
    int co = i & 31, ci = (i >> 5) & 31, t3 = i >> 10;
    KT[((size_t)t3*32 + co)*32 + ci] = kern[((size_t)t3*32 + ci)*32 + co];
}

// K3: reorder into bin-sorted SoA: X[p][32], W[p][9], GZ[p] (bin z, u8)
__global__ __launch_bounds__(256) void reorder_kernel(
    const float* __restrict__ x, const float* __restrict__ pos,
    const unsigned* __restrict__ offs, const unsigned* __restrict__ binA,
    const unsigned* __restrict__ rankA,
    float* __restrict__ X, float* __restrict__ W, unsigned char* __restrict__ GZ,
    int total)
{
    int gp = blockIdx.x*256 + threadIdx.x;
    if (gp >= total) return;
    unsigned bin = binA[gp];
    unsigned dst = offs[bin] + rankA[gp];
    const float4* xs = (const float4*)(x + (size_t)gp*32);
    float4* xd = (float4*)(X + (size_t)dst*32);
    #pragma unroll
    for (int i = 0; i < 8; ++i) xd[i] = xs[i];
    float px = pos[gp*3+0]*64.f, py = pos[gp*3+1]*64.f, pz = pos[gp*3+2]*64.f;
    int bx = (int)px, by = (int)py, bz = (int)pz;
    float fx = px-bx-0.5f, fy = py-by-0.5f, fz = pz-bz-0.5f;
    float* w = W + (size_t)dst*9;
    w[0]=0.5f*(0.5f-fx)*(0.5f-fx); w[1]=0.75f-fx*fx; w[2]=0.5f*(0.5f+fx)*(0.5f+fx);
    w[3]=0.5f*(0.5f-fy)*(0.5f-fy); w[4]=0.75f-fy*fy; w[5]=0.5f*(0.5f+fy)*(0.5f+fy);
    w[6]=0.5f*(0.5f-fz)*(0.5f-fz); w[7]=0.75f-fz*fz; w[8]=0.5f*(0.5f+fz)*(0.5f+fz);
    GZ[dst] = (unsigned char)(bin & 63u);
}

// K4 v6: gather. Block = (b, cx, cy) full z-column. Per t=(oi,oj): the
// column's particles are CONTIGUOUS [offs[col], offs[col+64]). kreg[3][32]
// (96 VGPRs) pinned resident for the whole t; per particle: 8 float4 X loads
// unpacked + pinned (batched, one waitcnt), 96 FMAs (3 independent chains),
// 3 ds_add_f32 into tile[gz+ok][co]. launch_bounds(256,2): 256-VGPR cap so
// nothing spills (r6/r7: occupancy-first allocator sank K into the loop).
__global__ __launch_bounds__(256, 2) void gather_kernel(
    const float* __restrict__ X, const float* __restrict__ W,
    const unsigned char* __restrict__ GZ, const unsigned* __restrict__ offs,
    const float* __restrict__ KT, const float* __restrict__ bias,
    float* __restrict__ out)
{
    __shared__ float tile[GD][33];              // 8712 B
    int bid = blockIdx.x;
    const int cy = bid % 66; bid /= 66;
    const int cx = bid % 66;
    const int b  = bid / 66;

    const int lane = threadIdx.x & 63;
    const int co   = lane & 31;
    const int slot = lane >> 5;                 // particle slot within wave
    const int w    = threadIdx.x >> 6;          // wave id 0..3
    const float bco = bias[co];

    for (int i = threadIdx.x; i < GD*33; i += 256) (&tile[0][0])[i] = 0.f;
    __syncthreads();

    for (int t = 0; t < 9; ++t) {               // t = oi*3 + oj
        const int oi = t/3, oj = t%3;
        const int gx = cx - oi, gy = cy - oj;
        if ((unsigned)gx > 63u || (unsigned)gy > 63u) continue;   // block-uniform

        const unsigned colb = (((unsigned)(b*64 + gx))*64u + (unsigned)gy)*64u;
        const unsigned s = offs[colb], e = offs[colb + 64];
        if (s == e) continue;

        // K columns for all 3 ok of this (oi,oj): 96 scalars, pinned.
        float kreg[3][32];
        #pragma unroll
        for (int ok = 0; ok < 3; ++ok) {
            const float4* kp = (const float4*)(KT + ((size_t)(t*3+ok)*32 + co)*32);
            #pragma unroll
            for (int i = 0; i < 8; ++i) {
                float4 v = kp[i];
                kreg[ok][4*i+0]=v.x; kreg[ok][4*i+1]=v.y; kreg[ok][4*i+2]=v.z; kreg[ok][4*i+3]=v.w;
            }
        }
        PIN32(kreg[0]); PIN32(kreg[1]); PIN32(kreg[2]);

        for (unsigned p = s + (unsigned)(w*2 + slot); p < e; p += 8) {
            const float4* xp = (const float4*)(X + (size_t)p*32);
            const float*  wp = W + (size_t)p*9;
            const int gz = (int)GZ[p];
            const float wxy = wp[oi]*wp[3+oj];
            const float wz0 = wp[6], wz1 = wp[7], wz2 = wp[8];

            // 8 batched float4 loads -> 32 pinned scalars (one waitcnt).
            float xx[32];
            #pragma unroll
            for (int i = 0; i < 8; ++i) {
                float4 v = xp[i];
                xx[4*i+0]=v.x; xx[4*i+1]=v.y; xx[4*i+2]=v.z; xx[4*i+3]=v.w;
            }
            PIN32(xx);

            // 3 independent 32-FMA chains
            float d0 = bco, d1 = bco, d2 = bco;
            #pragma unroll
            for (int ci = 0; ci < 32; ++ci) {
                const float xv = xx[ci];
                d0 += xv*kreg[0][ci];
                d1 += xv*kreg[1][ci];
                d2 += xv*kreg[2][ci];
            }
            float* tp = &tile[gz][co];          // rows gz, gz+1, gz+2 (<=65)
            atomicAdd(tp,      wxy*wz0*d0);     // ds_add_f32, conflict-free banks
            atomicAdd(tp + 33, wxy*wz1*d1);
            atomicAdd(tp + 66, wxy*wz2*d2);
        }
    }

    __syncthreads();
    const size_t obase = (size_t)b*32*GDHW + (size_t)(cx*GHW + cy*GD);
    for (int idx = threadIdx.x; idx < 32*GD; idx += 256) {
        const int co2 = idx / GD, z2 = idx % GD;    // consecutive lanes -> consecutive z
        out[obase + (size_t)co2*GDHW + z2] = tile[z2][co2];
    }
}

// ---------------- fallback: direct atomic scatter ----------------
__global__ __launch_bounds__(256) void p2g_fallback(
    const float* __restrict__ x, const float* __restrict__ pos,
    const float* __restrict__ kern, const float* __restrict__ bias,
    float* __restrict__ dst, int N, int nPairs)
{
    const int co   = threadIdx.x & 31;
    const int half = threadIdx.x >> 5;
    const float bco = bias[co];
    const int halvesTotal = gridDim.x * 8;

    for (int t = 0; t < 9; ++t) {
        const int oi = t / 3, oj = t - 3*oi;
        float kreg[3][32];
        #pragma unroll
        for (int ok = 0; ok < 3; ++ok) {
            const float* kp = kern + (size_t)(t*3 + ok)*1024 + co;
            #pragma unroll
            for (int ci = 0; ci < 32; ++ci) kreg[ok][ci] = kp[ci*32];
        }
        for (int pp = blockIdx.x*8 + half; pp < nPairs; pp += halvesTotal) {
            const int g0 = pp*2;
            float xr[2][32];
            #pragma unroll
            for (int p = 0; p < 2; ++p) {
                const float4* xp = (const float4*)(x + (size_t)(g0+p)*CI);
                #pragma unroll
                for (int i = 0; i < 8; ++i) {
                    float4 v = xp[i];
                    xr[p][4*i+0]=v.x; xr[p][4*i+1]=v.y; xr[p][4*i+2]=v.z; xr[p][4*i+3]=v.w;
                }
            }
            float wxy[2], wz[2][3]; int cb[2], bsel[2];
            #pragma unroll
            for (int p = 0; p < 2; ++p) {
                const int gp = g0 + p;
                float px = pos[gp*3+0]*64.f, py = pos[gp*3+1]*64.f, pz = pos[gp*3+2]*64.f;
                int bx = (int)px, by = (int)py, bz = (int)pz;
                float fx = px-bx-0.5f, fy = py-by-0.5f, fz = pz-bz-0.5f;
                float wx = (oi==0) ? 0.5f*(0.5f-fx)*(0.5f-fx) : (oi==1) ? 0.75f-fx*fx : 0.5f*(0.5f+fx)*(0.5f+fx);
                float wy = (oj==0) ? 0.5f*(0.5f-fy)*(0.5f-fy) : (oj==1) ? 0.75f-fy*fy : 0.5f*(0.5f+fy)*(0.5f+fy);
                wxy[p] = wx*wy;
                wz[p][0]=0.5f*(0.5f-fz)*(0.5f-fz); wz[p][1]=0.75f-fz*fz; wz[p][2]=0.5f*(0.5f+fz)*(0.5f+fz);
                cb[p]   = (bx+oi)*GHW + (by+oj)*GD + bz;
                bsel[p] = (gp >= N) ? 1 : 0;
            }
            float y[3][2];
            #pragma unroll
            for (int ok = 0; ok < 3; ++ok) { y[ok][0] = bco; y[ok][1] = bco; }
            #pragma unroll
            for (int ci = 0; ci < 32; ++ci) {
                float x0 = xr[0][ci], x1 = xr[1][ci];
                #pragma unroll
                for (int ok = 0; ok < 3; ++ok) {
                    float kv = kreg[ok][ci];
                    y[ok][0] += x0*kv; y[ok][1] += x1*kv;
                }
            }
            #pragma unroll
            for (int ok = 0; ok < 3; ++ok) {
                atomAdd(dst + ((size_t)(bsel[0]*32 + co))*GDHW + (size_t)(cb[0]+ok), wxy[0]*wz[0][ok]*y[ok][0]);
                atomAdd(dst + ((size_t)(bsel[1]*32 + co))*GDHW + (size_t)(cb[1]+ok), wxy[1]*wz[1][ok]*y[ok][1]);
            }
        }
    }
}

extern "C" void kernel_launch(void* const* d_in, const int* in_sizes, int n_in,
                              void* d_out, int out_size, void* d_ws, size_t ws_size,
                              hipStream_t stream) {
    const float* x    = (const float*)d_in[0];
    const float* pos  = (const float*)d_in[1];
    const float* kern = (const float*)d_in[2];
    const float* bias = (const float*)d_in[3];
    float* out = (float*)d_out;

    const int N     = in_sizes[0] / (2*CI);   // per-batch particle count
    const int total = 2*N;

    // workspace layout (bytes) -- stays under the proven-available 73.59 MB:
    // KT aliases counts (dead after scan1); GZ is u8.
    const size_t offX    = 0;                                   // X: total*32 f32
    const size_t offW    = offX + (size_t)total*32*4;           // W: total*9 f32
    const size_t offCnt  = offW + (size_t)total*9*4;            // counts: NBINS u32 (KT aliases)
    const size_t offOffs = offCnt + (size_t)NBINS*4;            // offs: NBINS+1 u32
    const size_t offBin  = (offOffs + (size_t)(NBINS+1)*4 + 255) & ~(size_t)255;
    const size_t offRank = offBin + (size_t)total*4;
    const size_t offBsum = offRank + (size_t)total*4;
    const size_t offGZ   = offBsum + (size_t)NSCAN_BLOCKS*4;
    const size_t wsNeed  = offGZ + (size_t)total + 256;

    if (ws_size >= wsNeed) {
        char* wsb = (char*)d_ws;
        float*    X      = (float*)   (wsb + offX);
        float*    W      = (float*)   (wsb + offW);
        unsigned* counts = (unsigned*)(wsb + offCnt);
        float*    KT     = (float*)   (wsb + offCnt);   // alias: counts dead after scan1
        unsigned* offs   = (unsigned*)(wsb + offOffs);
        unsigned* binA   = (unsigned*)(wsb + offBin);
        unsigned* rankA  = (unsigned*)(wsb + offRank);
        unsigned* bsum   = (unsigned*)(wsb + offBsum);
        unsigned char* GZ = (unsigned char*)(wsb + offGZ);

        (void)hipMemsetAsync(counts, 0, (size_t)NBINS*4, stream);
        const int pb = (total + 255)/256;
        hist_kernel   <<<dim3(pb),           dim3(256), 0, stream>>>(pos, counts, binA, rankA, N, total);
        scan1_kernel  <<<dim3(NSCAN_BLOCKS), dim3(256), 0, stream>>>(counts, offs, bsum);
        ktr_kernel    <<<dim3(108),          dim3(256), 0, stream>>>(kern, KT);   // after scan1!
        scan2_kernel  <<<dim3(1),            dim3(256), 0, stream>>>(bsum);
        scan3_kernel  <<<dim3(NSCAN_BLOCKS), dim3(256), 0, stream>>>(offs, bsum, total);
        reorder_kernel<<<dim3(pb),           dim3(256), 0, stream>>>(x, pos, offs, binA, rankA, X, W, GZ, total);
        gather_kernel <<<dim3(2*66*66),      dim3(256), 0, stream>>>(X, W, GZ, offs, KT, bias, out);
    } else {
        (void)hipMemsetAsync(out, 0, (size_t)out_size * sizeof(float), stream);
        const int nPairs = (total + 1) / 2;
        p2g_fallback<<<dim3(2048), dim3(256), 0, stream>>>(x, pos, kern, bias, out, N, nPairs);
    }
}